// Round 7
// baseline (383.525 us; speedup 1.0000x reference)
//
#include <hip/hip_runtime.h>
#include <hip/hip_bf16.h>
#include <hip/hip_cooperative_groups.h>

// GCN single cooperative kernel for MI355X (gfx950). All float I/O is FLOAT32.
//
// Algebra: y[b,n] = reg_b[b] + sum_e val_e * z[col_e, b]
//   z[n,b]  = relu( (A@X)[n,:] @ W0[b] ) . v1[b,:]
//   v1[b,h] = sum_c W1[b,h,c] * reg_w[b,c]
//
// Round 7: ONE hipLaunchCooperativeKernel with grid.sync() between phases:
//   P0 init (deg=0, x->bf16, W0^T bf16, v1)
//   P1 ELL scatter (atomics)
//   P2 spmm xa = A@X  (wave per row, TWO rows in flight per wave)
//   P3 gemm z = relu(xa@W0).v1  (64-row LDS tile, MFMA, B from L2)
//   P4 spmv y = A@z + regb (wave per row, two rows in flight)
// Kills all inter-node launch/drain overhead (round-6 lesson: keep gather
// TLP high; round 5 lesson: ~10us/node overhead dominated the pipeline).

#define NN 20000
#define EE 320000
#define BB 4
#define FF 128
#define HH 128
#define CC 64

typedef unsigned short u16;
typedef short short8 __attribute__((ext_vector_type(8)));
typedef float floatx4 __attribute__((ext_vector_type(4)));

namespace cg = cooperative_groups;

static __device__ __forceinline__ float b2f(u16 u) {
    union { unsigned int i; float f; } x;
    x.i = ((unsigned int)u) << 16;
    return x.f;
}

static __device__ __forceinline__ u16 f2b(float f) {
    __hip_bfloat16 h = __float2bfloat16(f);
    return *reinterpret_cast<u16*>(&h);
}

__global__ __launch_bounds__(256, 4) void k_all(
        const int* __restrict__ rows, const int* __restrict__ cols,
        const float* __restrict__ vals, const float* __restrict__ x,
        const float* __restrict__ w0, const float* __restrict__ w1,
        const float* __restrict__ regw, const float* __restrict__ regb,
        int* __restrict__ deg, uint2* __restrict__ epack,
        u16* __restrict__ xb, u16* __restrict__ w0t,
        float* __restrict__ v1, u16* __restrict__ xa,
        float* __restrict__ z, float* __restrict__ y) {
    __shared__ u16 sA[64 * 128];        // 16 KB (P3)
    __shared__ float part[4][64];       // 1 KB  (P3)

    cg::grid_group grid = cg::this_grid();
    const int nthr = gridDim.x * 256;
    const int gid0 = blockIdx.x * 256 + threadIdx.x;
    const int lane = threadIdx.x & 63;

    // ---- P0: init ----------------------------------------------------------
    for (int i = gid0; i < NN * FF / 4; i += nthr) {
        float4 v = ((const float4*)x)[i];
        ushort4 o;
        o.x = f2b(v.x); o.y = f2b(v.y); o.z = f2b(v.z); o.w = f2b(v.w);
        ((ushort4*)xb)[i] = o;
    }
    for (int i = gid0; i < NN; i += nthr) deg[i] = 0;
    for (int i = gid0; i < BB * FF * HH; i += nthr) {
        int b = i >> 14;
        int rem = i & 16383;
        int h = rem >> 7;
        int k = rem & 127;
        w0t[i] = f2b(w0[(b << 14) + (k << 7) + h]);    // w0t[b][h][k]
    }
    for (int i = gid0; i < BB * HH; i += nthr) {
        int b = i >> 7;
        int h = i & 127;
        const float* wrow = w1 + (b * HH + h) * CC;
        const float* rw = regw + b * CC;
        float s = 0.f;
#pragma unroll
        for (int c = 0; c < CC; ++c) s += wrow[c] * rw[c];
        v1[i] = s;
    }
    grid.sync();

    // ---- P1: ELL scatter ---------------------------------------------------
    for (int e = gid0; e < EE; e += nthr) {
        int r = rows[e];
        int p = atomicAdd(&deg[r], 1);
        epack[(r << 6) + p] = make_uint2((unsigned)cols[e], __float_as_uint(vals[e]));
    }
    grid.sync();

    // ---- P2: spmm xa = A @ X (two rows in flight per wave) -----------------
    {
        const int W = nthr >> 6;
        const int wid = gid0 >> 6;
        const int eg = lane >> 3;        // 8 edge groups
        const int fl = lane & 7;         // 8 feature blocks x 16 feats
        for (int r = wid; r < NN; r += 2 * W) {
            int rB = r + W;
            int dA = deg[r];
            int dB = (rB < NN) ? deg[rB] : 0;
            float aA[16], aB[16];
#pragma unroll
            for (int j = 0; j < 16; ++j) { aA[j] = 0.f; aB[j] = 0.f; }
            int qA = r << 6;
            int qB = rB << 6;
            int pA = eg, pB = eg;
            while (pA < dA || pB < dB) {
                bool hA = pA < dA, hB = pB < dB;
                uint2 eA, eB;
                if (hA) eA = epack[qA + pA];
                if (hB) eB = epack[qB + pB];
                if (hA) {
                    float v = __uint_as_float(eA.y);
                    const u16* xr = xb + (((size_t)eA.x) << 7) + fl * 16;
                    short8 x0 = *(const short8*)(xr);
                    short8 x1 = *(const short8*)(xr + 8);
#pragma unroll
                    for (int j = 0; j < 8; ++j) {
                        aA[j]     += v * b2f((u16)x0[j]);
                        aA[8 + j] += v * b2f((u16)x1[j]);
                    }
                }
                if (hB) {
                    float v = __uint_as_float(eB.y);
                    const u16* xr = xb + (((size_t)eB.x) << 7) + fl * 16;
                    short8 x0 = *(const short8*)(xr);
                    short8 x1 = *(const short8*)(xr + 8);
#pragma unroll
                    for (int j = 0; j < 8; ++j) {
                        aB[j]     += v * b2f((u16)x0[j]);
                        aB[8 + j] += v * b2f((u16)x1[j]);
                    }
                }
                pA += 8; pB += 8;
            }
#pragma unroll
            for (int j = 0; j < 16; ++j) {
                aA[j] += __shfl_xor(aA[j], 8);
                aA[j] += __shfl_xor(aA[j], 16);
                aA[j] += __shfl_xor(aA[j], 32);
                aB[j] += __shfl_xor(aB[j], 8);
                aB[j] += __shfl_xor(aB[j], 16);
                aB[j] += __shfl_xor(aB[j], 32);
            }
            if (eg == 0) {
                short8 o0, o1;
#pragma unroll
                for (int j = 0; j < 8; ++j) {
                    o0[j] = (short)f2b(aA[j]);
                    o1[j] = (short)f2b(aA[8 + j]);
                }
                u16* orow = xa + (((size_t)r) << 7) + fl * 16;
                *(short8*)(orow) = o0;
                *(short8*)(orow + 8) = o1;
                if (rB < NN) {
#pragma unroll
                    for (int j = 0; j < 8; ++j) {
                        o0[j] = (short)f2b(aB[j]);
                        o1[j] = (short)f2b(aB[8 + j]);
                    }
                    u16* orowB = xa + (((size_t)rB) << 7) + fl * 16;
                    *(short8*)(orowB) = o0;
                    *(short8*)(orowB + 8) = o1;
                }
            }
        }
    }
    grid.sync();

    // ---- P3: gemm z[n,b] = relu(xa[n,:] @ W0[b]) . v1[b,:] -----------------
    // unit = (64-row tile, batch b). A in LDS (16-slot XOR swizzle,
    // conflict-free ds_read_b128), B streamed from L2-hot w0t.
    {
        const int t = threadIdx.x;
        const int wv = t >> 6;           // wave = col quarter (32 cols)
        const int g = lane >> 4;
        const int lr = lane & 15;
        const int nunits = ((NN + 63) / 64) * BB;   // 313*4
        for (int u = blockIdx.x; u < nunits; u += gridDim.x) {
            int tile = u >> 2;
            int b = u & 3;
            int base = tile * 64;
            // stage A: 64 rows x 128 cols bf16, swizzled 16B slots
#pragma unroll
            for (int it = 0; it < 4; ++it) {
                int idx = it * 256 + t;      // 0..1023
                int rr = idx >> 4;           // 0..63
                int c = idx & 15;            // 16B slot
                int sl = c ^ (rr & 15);
                uint4 av = make_uint4(0u, 0u, 0u, 0u);
                int grow = base + rr;
                if (grow < NN) av = *(const uint4*)(xa + (((size_t)grow) << 7) + c * 8);
                *(uint4*)(&sA[rr * 128 + sl * 8]) = av;
            }
            __syncthreads();

            floatx4 acc[4][2];
#pragma unroll
            for (int i = 0; i < 4; ++i)
#pragma unroll
                for (int j = 0; j < 2; ++j) acc[i][j] = (floatx4){0.f, 0.f, 0.f, 0.f};

#pragma unroll
            for (int kk = 0; kk < 4; ++kk) {
                short8 a[4], bf[2];
#pragma unroll
                for (int i = 0; i < 4; ++i) {
                    int row = i * 16 + lr;
                    int slot = (kk * 4 + g) ^ (row & 15);
                    a[i] = *(const short8*)(&sA[row * 128 + slot * 8]);
                }
#pragma unroll
                for (int j = 0; j < 2; ++j) {
                    int col = wv * 32 + j * 16 + lr;
                    bf[j] = *(const short8*)(w0t + (((size_t)b) << 14) + (col << 7) + kk * 32 + g * 8);
                }
#pragma unroll
                for (int i = 0; i < 4; ++i)
#pragma unroll
                    for (int j = 0; j < 2; ++j)
                        acc[i][j] = __builtin_amdgcn_mfma_f32_16x16x32_bf16(a[i], bf[j], acc[i][j], 0, 0, 0);
            }

            float vv[2];
#pragma unroll
            for (int j = 0; j < 2; ++j) vv[j] = v1[b * 128 + wv * 32 + j * 16 + lr];

#pragma unroll
            for (int i = 0; i < 4; ++i) {
#pragma unroll
                for (int r = 0; r < 4; ++r) {
                    float s = fmaxf(acc[i][0][r], 0.f) * vv[0] + fmaxf(acc[i][1][r], 0.f) * vv[1];
                    s += __shfl_xor(s, 1);
                    s += __shfl_xor(s, 2);
                    s += __shfl_xor(s, 4);
                    s += __shfl_xor(s, 8);
                    if (lr == 0) part[wv][i * 16 + g * 4 + r] = s;
                }
            }
            __syncthreads();
            if (t < 64) {
                int grow = base + t;
                if (grow < NN)
                    z[grow * 4 + b] = part[0][t] + part[1][t] + part[2][t] + part[3][t];
            }
            __syncthreads();
        }
    }
    grid.sync();

    // ---- P4: spmv y[b,r] = regb[b] + sum val*z[col,b] (two rows/wave) ------
    {
        const int W = nthr >> 6;
        const int wid = gid0 >> 6;
        const int eg = lane >> 2;        // 16 edge groups
        const int b = lane & 3;
        for (int r = wid; r < NN; r += 2 * W) {
            int rB = r + W;
            int dA = deg[r];
            int dB = (rB < NN) ? deg[rB] : 0;
            float sA_ = 0.f, sB_ = 0.f;
            int qA = r << 6;
            int qB = rB << 6;
            int pA = eg, pB = eg;
            while (pA < dA || pB < dB) {
                bool hA = pA < dA, hB = pB < dB;
                uint2 eA, eB;
                if (hA) eA = epack[qA + pA];
                if (hB) eB = epack[qB + pB];
                if (hA) sA_ += __uint_as_float(eA.y) * z[(((size_t)eA.x) << 2) + b];
                if (hB) sB_ += __uint_as_float(eB.y) * z[(((size_t)eB.x) << 2) + b];
                pA += 16; pB += 16;
            }
            sA_ += __shfl_xor(sA_, 4);
            sA_ += __shfl_xor(sA_, 8);
            sA_ += __shfl_xor(sA_, 16);
            sA_ += __shfl_xor(sA_, 32);
            sB_ += __shfl_xor(sB_, 4);
            sB_ += __shfl_xor(sB_, 8);
            sB_ += __shfl_xor(sB_, 16);
            sB_ += __shfl_xor(sB_, 32);
            if (lane < 4) {
                y[lane * NN + r] = sA_ + regb[lane];
                if (rB < NN) y[lane * NN + rB] = sB_ + regb[lane];
            }
        }
    }
}

// ---- launch ----------------------------------------------------------------

extern "C" void kernel_launch(void* const* d_in, const int* in_sizes, int n_in,
                              void* d_out, int out_size, void* d_ws, size_t ws_size,
                              hipStream_t stream) {
    const float* x    = (const float*)d_in[0];
    const int*   rows = (const int*)d_in[1];
    const int*   cols = (const int*)d_in[2];
    const float* vals = (const float*)d_in[3];
    const float* w0   = (const float*)d_in[4];
    const float* w1   = (const float*)d_in[5];
    const float* regw = (const float*)d_in[6];
    const float* regb = (const float*)d_in[7];
    float* y = (float*)d_out;

    char* ws = (char*)d_ws;
    int*   deg   = (int*)(ws + 0);                   //     81,920 B
    uint2* epack = (uint2*)(ws + 81920);             // 10,240,000 B
    u16*   xb    = (u16*)(ws + 10321920);            //  5,120,000 B
    u16*   xa    = (u16*)(ws + 15441920);            //  5,120,000 B
    u16*   w0t   = (u16*)(ws + 20561920);            //    131,072 B
    float* v1    = (float*)(ws + 20692992);          //      2,048 B
    float* z     = (float*)(ws + 20695040);          //    320,000 B

    int maxB = 0;
    hipOccupancyMaxActiveBlocksPerMultiprocessor(&maxB, k_all, 256, 0);
    if (maxB < 1) maxB = 1;
    int grid = maxB * 256;
    if (grid > 2048) grid = 2048;

    void* args[] = {(void*)&rows, (void*)&cols, (void*)&vals, (void*)&x,
                    (void*)&w0, (void*)&w1, (void*)&regw, (void*)&regb,
                    (void*)&deg, (void*)&epack, (void*)&xb, (void*)&w0t,
                    (void*)&v1, (void*)&xa, (void*)&z, (void*)&y};
    hipLaunchCooperativeKernel((const void*)k_all, dim3(grid), dim3(256),
                               args, 0, stream);
}

// Round 8
// 137.287 us; speedup vs baseline: 2.7936x; 2.7936x over previous
//
#include <hip/hip_runtime.h>
#include <hip/hip_bf16.h>

// GCN fused pipeline for MI355X (gfx950). All float I/O is FLOAT32.
//
// Algebra: y[b,n] = reg_b[b] + sum_e val_e * z[col_e, b]
//   z[n,b]  = relu( (A@X)[n,:] @ W0[b] ) . v1[b,:]
//   v1[b,h] = sum_c W1[b,h,c] * reg_w[b,c]
//
// Round 8: 4 graph nodes (per-node cost measured ~16-18us across rounds):
//   memset(deg) -> k_init (ELL scatter + x->bf16 + W0^T + v1)
//   -> k_spmm_gemm (16 rows/block, 1250 blocks: gather keeps round-5 TLP;
//      M=16 MFMA gemm, B from L2, epilogue writes z directly)
//   -> k_spmv.
// Round-7 lesson: cooperative grid.sync costs ~90us each on 8 XCDs — never.
// Round-6 lesson: fusion must preserve gather TLP (5000+ waves).

#define NN 20000
#define EE 320000
#define BB 4
#define FF 128
#define HH 128
#define CC 64

typedef unsigned short u16;
typedef short short8 __attribute__((ext_vector_type(8)));
typedef float floatx4 __attribute__((ext_vector_type(4)));

static __device__ __forceinline__ float b2f(u16 u) {
    union { unsigned int i; float f; } x;
    x.i = ((unsigned int)u) << 16;
    return x.f;
}

static __device__ __forceinline__ u16 f2b(float f) {
    __hip_bfloat16 h = __float2bfloat16(f);
    return *reinterpret_cast<u16*>(&h);
}

// ---- init: ELL scatter + x->bf16 + W0^T bf16 + v1 (deg pre-zeroed) ---------

__global__ __launch_bounds__(256) void k_init(
        const int* __restrict__ rows, const int* __restrict__ cols,
        const float* __restrict__ vals, int* __restrict__ deg,
        uint2* __restrict__ epack,
        const float* __restrict__ x, u16* __restrict__ xb,
        const float* __restrict__ w0, const float* __restrict__ w1,
        const float* __restrict__ regw, u16* __restrict__ w0t,
        float* __restrict__ v1) {
    int gid = blockIdx.x * 256 + threadIdx.x;
    if (gid < EE) {
        int r = rows[gid];
        int p = atomicAdd(&deg[r], 1);
        if (p < 64)
            epack[(r << 6) + p] = make_uint2((unsigned)cols[gid], __float_as_uint(vals[gid]));
    }
    if (gid < NN * FF / 4) {
        float4 v = ((const float4*)x)[gid];
        ushort4 o;
        o.x = f2b(v.x); o.y = f2b(v.y); o.z = f2b(v.z); o.w = f2b(v.w);
        ((ushort4*)xb)[gid] = o;
    }
    if (gid < BB * FF * HH) {
        int b = gid >> 14;
        int rem = gid & 16383;
        int h = rem >> 7;
        int k = rem & 127;
        w0t[gid] = f2b(w0[(b << 14) + (k << 7) + h]);   // w0t[b][h][k] = w0[b][k][h]
    }
    if (gid < BB * HH) {
        int b = gid >> 7;
        int h = gid & 127;
        const float* wrow = w1 + (b * HH + h) * CC;
        const float* rw = regw + b * CC;
        float s = 0.f;
#pragma unroll
        for (int c = 0; c < CC; ++c) s += wrow[c] * rw[c];
        v1[gid] = s;
    }
}

// ---- fused SpMM + GEMM, TLP-preserving -------------------------------------
// Block = 16 rows, 256 threads (4 waves), 1250 blocks = 5000 waves.
// Phase A: wave wv aggregates rows base+wv*4..+3, all 4 interleaved in regs;
//          lane = (edge group 0..3) x (feat block 0..15, 8 feats = 16B).
//          Result -> bf16 LDS sA[16][128] with 16-slot XOR swizzle.
// Phase B: wave = batch b. M=16 x N=128 gemm via 16x16x32 MFMA; A from LDS
//          (conflict-free), B streamed from L2-hot w0t. Epilogue computes
//          z[n,b] = sum_col relu(.)*v1 directly (no LDS, no xa buffer).

__global__ __launch_bounds__(256, 4) void k_spmm_gemm(
        const int* __restrict__ deg, const uint2* __restrict__ epack,
        const u16* __restrict__ xb, const u16* __restrict__ w0t,
        const float* __restrict__ v1, float* __restrict__ z) {
    __shared__ u16 sA[16 * 128];   // 4 KB

    const int base = blockIdx.x * 16;
    const int t = threadIdx.x;
    const int wv = t >> 6;
    const int lane = t & 63;

    // ---- Phase A ----
    {
        const int eg = lane >> 4;        // 4 edge groups
        const int fl = lane & 15;        // 16 feat blocks x 8 feats
        int r[4], d[4];
#pragma unroll
        for (int i = 0; i < 4; ++i) {
            r[i] = base + wv * 4 + i;
            int dd = (r[i] < NN) ? deg[r[i]] : 0;
            d[i] = dd > 64 ? 64 : dd;
        }
        float acc[4][8];
#pragma unroll
        for (int i = 0; i < 4; ++i)
#pragma unroll
            for (int j = 0; j < 8; ++j) acc[i][j] = 0.f;

        int dmx = max(max(d[0], d[1]), max(d[2], d[3]));
        for (int p = eg; p < dmx; p += 4) {
#pragma unroll
            for (int i = 0; i < 4; ++i) {
                if (p < d[i]) {
                    uint2 ep = epack[(r[i] << 6) + p];
                    float v = __uint_as_float(ep.y);
                    short8 xv = *(const short8*)(xb + (((size_t)ep.x) << 7) + fl * 8);
#pragma unroll
                    for (int j = 0; j < 8; ++j) acc[i][j] += v * b2f((u16)xv[j]);
                }
            }
        }
#pragma unroll
        for (int i = 0; i < 4; ++i)
#pragma unroll
            for (int j = 0; j < 8; ++j) {
                acc[i][j] += __shfl_xor(acc[i][j], 16);
                acc[i][j] += __shfl_xor(acc[i][j], 32);
            }
        if (eg == 0) {
#pragma unroll
            for (int i = 0; i < 4; ++i) {
                short8 o;
#pragma unroll
                for (int j = 0; j < 8; ++j) o[j] = (short)f2b(acc[i][j]);
                int lr0 = wv * 4 + i;
                *(short8*)(&sA[lr0 * 128 + (fl ^ lr0) * 8]) = o;
            }
        }
    }
    __syncthreads();

    // ---- Phase B: wave = batch ----
    {
        const int b = wv;
        const int g = lane >> 4;
        const int lr = lane & 15;

        floatx4 acc2[8];
#pragma unroll
        for (int j = 0; j < 8; ++j) acc2[j] = (floatx4){0.f, 0.f, 0.f, 0.f};

#pragma unroll
        for (int kk = 0; kk < 4; ++kk) {
            short8 a = *(const short8*)(&sA[lr * 128 + ((kk * 4 + g) ^ lr) * 8]);
#pragma unroll
            for (int j = 0; j < 8; ++j) {
                short8 bf = *(const short8*)(w0t + (((size_t)b) << 14) +
                                             ((j * 16 + lr) << 7) + kk * 32 + g * 8);
                acc2[j] = __builtin_amdgcn_mfma_f32_16x16x32_bf16(a, bf, acc2[j], 0, 0, 0);
            }
        }

        float vv[8];
#pragma unroll
        for (int j = 0; j < 8; ++j) vv[j] = v1[b * 128 + j * 16 + lr];

#pragma unroll
        for (int rr = 0; rr < 4; ++rr) {
            float s = 0.f;
#pragma unroll
            for (int j = 0; j < 8; ++j) s += fmaxf(acc2[j][rr], 0.f) * vv[j];
            s += __shfl_xor(s, 1);
            s += __shfl_xor(s, 2);
            s += __shfl_xor(s, 4);
            s += __shfl_xor(s, 8);
            if (lr == 0) {
                int grow = base + g * 4 + rr;
                if (grow < NN) z[grow * 4 + b] = s;
            }
        }
    }
}

// ---- y[b,r] = reg_b[b] + sum_e val * z[col,b] : wave per row (ELL) ---------

__global__ __launch_bounds__(256) void k_spmv(
        const int* __restrict__ deg, const uint2* __restrict__ epack,
        const float* __restrict__ z, const float* __restrict__ regb,
        float* __restrict__ y) {
    int wave = (blockIdx.x * 256 + threadIdx.x) >> 6;
    int lane = threadIdx.x & 63;
    if (wave >= NN) return;
    int d = deg[wave];
    if (d > 64) d = 64;
    int eg = lane >> 2;
    int b = lane & 3;
    int p0 = wave << 6;
    float acc = 0.f;
    for (int p = eg; p < d; p += 16) {
        uint2 ep = epack[p0 + p];
        acc += __uint_as_float(ep.y) * z[(((size_t)ep.x) << 2) + b];
    }
    acc += __shfl_xor(acc, 4);
    acc += __shfl_xor(acc, 8);
    acc += __shfl_xor(acc, 16);
    acc += __shfl_xor(acc, 32);
    if (lane < 4) y[lane * NN + wave] = acc + regb[lane];
}

// ---- launch ----------------------------------------------------------------

extern "C" void kernel_launch(void* const* d_in, const int* in_sizes, int n_in,
                              void* d_out, int out_size, void* d_ws, size_t ws_size,
                              hipStream_t stream) {
    const float* x    = (const float*)d_in[0];
    const int*   rows = (const int*)d_in[1];
    const int*   cols = (const int*)d_in[2];
    const float* vals = (const float*)d_in[3];
    const float* w0   = (const float*)d_in[4];
    const float* w1   = (const float*)d_in[5];
    const float* regw = (const float*)d_in[6];
    const float* regb = (const float*)d_in[7];
    float* y = (float*)d_out;

    char* ws = (char*)d_ws;
    int*   deg   = (int*)(ws + 0);                   //     81,920 B
    uint2* epack = (uint2*)(ws + 81920);             // 10,240,000 B (ELL 20000x64x8)
    u16*   xb    = (u16*)(ws + 10321920);            //  5,120,000 B
    u16*   w0t   = (u16*)(ws + 15441920);            //    131,072 B
    float* v1    = (float*)(ws + 15572992);          //      2,048 B
    float* z     = (float*)(ws + 15575040);          //    320,000 B
    // total ~15.9 MB

    hipMemsetAsync(deg, 0, NN * sizeof(int), stream);
    k_init<<<(NN * FF / 4 + 255) / 256, 256, 0, stream>>>(rows, cols, vals, deg, epack,
                                                          x, xb, w0, w1, regw, w0t, v1);
    k_spmm_gemm<<<NN / 16, 256, 0, stream>>>(deg, epack, xb, w0t, v1, z);
    k_spmv<<<(NN * 64 + 255) / 256, 256, 0, stream>>>(deg, epack, z, regb, y);
}